// Round 4
// baseline (458.839 us; speedup 1.0000x reference)
//
#include <hip/hip_runtime.h>

typedef unsigned long long u64;

#define N_SP 3136          // 56*56
#define C_IN 256
#define C_OUT 256
#define BATCH 32
#define HT 8               // rows per conv block-tile
#define NPOS (BATCH * N_SP)

// ---------------------------------------------------------------- weight prep
// One block per output channel o (256 threads = one per input channel).
// wc = w - mean_over_Cin; pack sign bits; alpha[o] = mean|clamp(wc)| in double.
// wbits layout: [c][word][tap] so a conv wave's 9 taps are contiguous.
// Block 0 also zeroes the stats accumulators (runs before conv in stream order).
__global__ __launch_bounds__(256) void prep_weights(const float* __restrict__ w,
                                                    u64* __restrict__ wbits,
                                                    double* __restrict__ alpha,
                                                    u64* __restrict__ stats) {
    const int o = blockIdx.x;
    const int i = threadIdx.x;           // input channel
    const int lane = i & 63, wave = i >> 6;
    if (o == 0) { stats[i] = 0ull; stats[256 + i] = 0ull; }
    __shared__ double red[256];
    __shared__ double mean[9];

    float wv[9];
    const float* wp = w + ((size_t)o * C_IN + i) * 9;
#pragma unroll
    for (int t = 0; t < 9; ++t) wv[t] = wp[t];

    double asum = 0.0;
    for (int t = 0; t < 9; ++t) {
        red[i] = (double)wv[t];
        __syncthreads();
        for (int s = 128; s > 0; s >>= 1) {
            if (i < s) red[i] += red[i + s];
            __syncthreads();
        }
        if (i == 0) mean[t] = red[0] * (1.0 / 256.0);
        __syncthreads();
        double wc = (double)wv[t] - mean[t];
        u64 m = __ballot(wc > 0.0);
        if (lane == 0) wbits[((size_t)o * 4 + wave) * 9 + t] = m;
        double aw = fabs(wc);
        if (aw > 1.0) aw = 1.0;
        asum += aw;
        __syncthreads();   // before red reuse
    }
    red[i] = asum;
    __syncthreads();
    for (int s = 128; s > 0; s >>= 1) {
        if (i < s) red[i] += red[i + s];
        __syncthreads();
    }
    if (i == 0) alpha[o] = red[0] * (1.0 / 2304.0);
}

// ---------------------------------------------------------------- pack x signs
// grid (392, 4): blockIdx.y = word. Planar xbits layout [word][b*N_SP + sp]:
// both the reads here and the conv's row loads are fully coalesced.
__global__ __launch_bounds__(256) void pack_x(const float* __restrict__ x,
                                              u64* __restrict__ xbits) {
    const int pos = blockIdx.x * 256 + threadIdx.x;    // 0 .. 100351
    const int word = blockIdx.y;                       // 0..3
    const int b = pos / N_SP;
    const int sp = pos - b * N_SP;
    const float* xp = x + ((size_t)b * C_IN + word * 64) * N_SP + sp;
    u64 m = 0;
#pragma unroll
    for (int j = 0; j < 64; ++j) {
        m |= (u64)(xp[(size_t)j * N_SP] > 0.0f) << j;
    }
    xbits[(size_t)word * NPOS + pos] = m;
}

// ---------------------------------------------------------------- popcount conv
// grid (224, 256): x = spatial tile (32 b x 7 row-tiles), y = output channel.
// Block 256 = 4 waves; wave = one 64-channel word; lane = output column.
// Weights are wave-uniform -> forced into SGPRs via readfirstlane (the VGPR
// allocator rematerialized vector-resident weights from memory in R1/R3;
// scalar regs are plentiful and v_xor takes an SGPR operand for free).
// Per-word partial mismatch counts combine across waves through LDS.
__global__ __launch_bounds__(256, 4) void conv_popc(const u64* __restrict__ xbits,
                                                    const u64* __restrict__ wbits,
                                                    float* __restrict__ out,
                                                    u64* __restrict__ stats) {
    const int wave = threadIdx.x >> 6;   // word index
    const int lane = threadIdx.x & 63;
    const int tile = blockIdx.x;
    const int b = tile / 7;
    const int h0 = (tile % 7) * HT;
    const int c = blockIdx.y;
    const int w = lane;
    const bool active = (w < 56);
    const int wcl = active ? w : 55;

    __shared__ int psh[4 * HT * 64];     // [word][row][lane] partial mismatches
    __shared__ u64 sred[8];

    // 9 taps for (c, word) -> 18 scalar registers
    unsigned wlo[9], whi[9];
    {
        const u64* wp = wbits + ((size_t)c * 4 + wave) * 9;
#pragma unroll
        for (int t = 0; t < 9; ++t) {
            u64 v = wp[t];
            wlo[t] = __builtin_amdgcn_readfirstlane((unsigned)v);
            whi[t] = __builtin_amdgcn_readfirstlane((unsigned)(v >> 32));
        }
    }

    // planar xbits: this word's plane, this batch image
    const u64* xb = xbits + (size_t)wave * NPOS + (size_t)b * N_SP;
    u64 a0 = 0, a1, a2;
    a1 = xb[h0 * 56 + wcl];
    a2 = xb[(h0 + 1) * 56 + wcl];
    if (h0 > 0) a0 = xb[(h0 - 1) * 56 + wcl];

#pragma unroll
    for (int hh = 0; hh < HT; ++hh) {
        const int h = h0 + hh;
        int Q0 = 0, Q1 = 0, Q2 = 0;
        if (h > 0) {
            unsigned lo = (unsigned)a0, hi = (unsigned)(a0 >> 32);
            Q0 += __popc(lo ^ wlo[0]) + __popc(hi ^ whi[0]);
            Q1 += __popc(lo ^ wlo[1]) + __popc(hi ^ whi[1]);
            Q2 += __popc(lo ^ wlo[2]) + __popc(hi ^ whi[2]);
        }
        {
            unsigned lo = (unsigned)a1, hi = (unsigned)(a1 >> 32);
            Q0 += __popc(lo ^ wlo[3]) + __popc(hi ^ whi[3]);
            Q1 += __popc(lo ^ wlo[4]) + __popc(hi ^ whi[4]);
            Q2 += __popc(lo ^ wlo[5]) + __popc(hi ^ whi[5]);
        }
        if (h < 55) {
            unsigned lo = (unsigned)a2, hi = (unsigned)(a2 >> 32);
            Q0 += __popc(lo ^ wlo[6]) + __popc(hi ^ whi[6]);
            Q1 += __popc(lo ^ wlo[7]) + __popc(hi ^ whi[7]);
            Q2 += __popc(lo ^ wlo[8]) + __popc(hi ^ whi[8]);
        }
        if (!active) { Q0 = 0; Q1 = 0; Q2 = 0; }
        int L = __shfl_up(Q0, 1);
        if (lane == 0) L = 0;
        int R = __shfl_down(Q2, 1);      // lane 55 reads lane 56 (zeroed)
        psh[(wave * HT + hh) * 64 + lane] = L + Q1 + R;
        if (hh < HT - 1) {
            a0 = a1; a1 = a2;
            if (h + 2 < 56) a2 = xb[(h + 2) * 56 + wcl];
        }
    }
    __syncthreads();

    // epilogue: each wave finalizes rows {wave*2, wave*2+1}
    int isum = 0;
    unsigned usq = 0;
    float* outc = out + ((size_t)b * C_OUT + c) * N_SP;
    const int vc = 3 - (w == 0) - (w == 55);
    if (active) {
#pragma unroll
        for (int i = 0; i < 2; ++i) {
            const int row = wave * 2 + i;
            const int h = h0 + row;
            const int nr = (h > 0) + 1 + (h < 55);
            int P = psh[(0 * HT + row) * 64 + lane]
                  + psh[(1 * HT + row) * 64 + lane]
                  + psh[(2 * HT + row) * 64 + lane]
                  + psh[(3 * HT + row) * 64 + lane];
            int S = ((nr * vc) << 8) - (P << 1);   // exact integer conv sum
            outc[h * 56 + w] = (float)S;
            isum += S;
            usq += (unsigned)(S * S);
        }
    }
    // wave reduce (|isum| per wave < 2^19, usq < 2^30)
#pragma unroll
    for (int off = 32; off > 0; off >>= 1) {
        isum += __shfl_down(isum, off);
        usq += (unsigned)__shfl_down((int)usq, off);
    }
    if (lane == 0) {
        sred[wave] = (u64)(long long)isum;
        sred[4 + wave] = (u64)usq;
    }
    __syncthreads();
    if (threadIdx.x == 0) {
        long long s1 = (long long)sred[0] + (long long)sred[1]
                     + (long long)sred[2] + (long long)sred[3];
        u64 s2 = sred[4] + sred[5] + sred[6] + sred[7];
        atomicAdd(&stats[c], (u64)s1);
        atomicAdd(&stats[C_OUT + c], s2);
    }
}

// ---------------------------------------------------------------- BN consts
__global__ void make_consts(const u64* __restrict__ stats,
                            const double* __restrict__ alpha,
                            const float* __restrict__ gamma,
                            const float* __restrict__ beta,
                            double* __restrict__ AB) {
    const int c = threadIdx.x;
    const double N = (double)(BATCH * N_SP);
    double s1 = (double)(long long)stats[c];
    double s2 = (double)(long long)stats[C_OUT + c];
    double mu = s1 / N;
    double var = s2 / N - mu * mu;
    double a = alpha[c];
    double vy = a * a * var;
    double scale = (double)gamma[c] / sqrt(vy + 1e-5);
    double A = a * scale;
    double B = (double)beta[c] - A * mu;
    AB[c] = A;
    AB[C_OUT + c] = B;
}

// ---------------------------------------------------------------- finalize
// In-place: d_out holds exact-integer S as float; out = (A*S+B > 0) ? 1 : 0.
__global__ __launch_bounds__(256) void finalize(float* __restrict__ out,
                                                const double* __restrict__ AB) {
    const unsigned i4 = blockIdx.x * 256 + threadIdx.x;   // 0 .. 6422527
    const unsigned e = i4 << 2;                            // element base
    const int c = (int)((e / N_SP) & (C_OUT - 1));         // 3136 | 4 -> c uniform in float4
    const double A = AB[c];
    const double B = AB[C_OUT + c];
    float4 v = ((float4*)out)[i4];
    v.x = (A * (double)v.x + B) > 0.0 ? 1.0f : 0.0f;
    v.y = (A * (double)v.y + B) > 0.0 ? 1.0f : 0.0f;
    v.z = (A * (double)v.z + B) > 0.0 ? 1.0f : 0.0f;
    v.w = (A * (double)v.w + B) > 0.0 ? 1.0f : 0.0f;
    ((float4*)out)[i4] = v;
}

// ---------------------------------------------------------------- launch
extern "C" void kernel_launch(void* const* d_in, const int* in_sizes, int n_in,
                              void* d_out, int out_size, void* d_ws, size_t ws_size,
                              hipStream_t stream) {
    const float* x      = (const float*)d_in[0];
    const float* weight = (const float*)d_in[1];
    const float* bias   = (const float*)d_in[2];   (void)bias;  // cancels in BN
    const float* gamma  = (const float*)d_in[3];
    const float* beta   = (const float*)d_in[4];
    float* out = (float*)d_out;

    char* ws = (char*)d_ws;
    u64*    stats = (u64*)(ws);                 // [512]
    double* alpha = (double*)(ws + 4096);       // [256]
    double* AB    = (double*)(ws + 8192);       // [512]
    u64*    wbits = (u64*)(ws + 16384);         // [256*4*9]
    u64*    xbits = (u64*)(ws + 98304);         // [4][32*3136]

    prep_weights<<<C_OUT, 256, 0, stream>>>(weight, wbits, alpha, stats);
    pack_x<<<dim3(BATCH * N_SP / 256, 4), 256, 0, stream>>>(x, xbits);
    conv_popc<<<dim3(BATCH * 7, C_OUT), 256, 0, stream>>>(xbits, wbits, out, stats);
    make_consts<<<1, C_OUT, 0, stream>>>(stats, alpha, gamma, beta, AB);
    finalize<<<(out_size / 4) / 256, 256, 0, stream>>>(out, AB);
}

// Round 5
// 411.794 us; speedup vs baseline: 1.1142x; 1.1142x over previous
//
#include <hip/hip_runtime.h>

typedef unsigned long long u64;

#define N_SP 3136          // 56*56
#define C_IN 256
#define C_OUT 256
#define BATCH 32
#define HT 8               // rows per conv wave-tile
#define NPOS (BATCH * N_SP)

// ---------------------------------------------------------------- weight prep
// One block per output channel o (256 threads = one per input channel).
// wc = w - mean_over_Cin; pack sign bits; alpha[o] = mean|clamp(wc)| in double.
// wbits layout: [c][tap][word]. Block 0 also zeroes the stats accumulators.
__global__ __launch_bounds__(256) void prep_weights(const float* __restrict__ w,
                                                    u64* __restrict__ wbits,
                                                    double* __restrict__ alpha,
                                                    u64* __restrict__ stats) {
    const int o = blockIdx.x;
    const int i = threadIdx.x;           // input channel
    const int lane = i & 63, wave = i >> 6;
    if (o == 0) { stats[i] = 0ull; stats[256 + i] = 0ull; }
    __shared__ double red[256];
    __shared__ double mean[9];

    float wv[9];
    const float* wp = w + ((size_t)o * C_IN + i) * 9;
#pragma unroll
    for (int t = 0; t < 9; ++t) wv[t] = wp[t];

    double asum = 0.0;
    for (int t = 0; t < 9; ++t) {
        red[i] = (double)wv[t];
        __syncthreads();
        for (int s = 128; s > 0; s >>= 1) {
            if (i < s) red[i] += red[i + s];
            __syncthreads();
        }
        if (i == 0) mean[t] = red[0] * (1.0 / 256.0);
        __syncthreads();
        double wc = (double)wv[t] - mean[t];
        u64 m = __ballot(wc > 0.0);
        if (lane == 0) wbits[((size_t)o * 9 + t) * 4 + wave] = m;
        double aw = fabs(wc);
        if (aw > 1.0) aw = 1.0;
        asum += aw;
        __syncthreads();   // before red reuse
    }
    red[i] = asum;
    __syncthreads();
    for (int s = 128; s > 0; s >>= 1) {
        if (i < s) red[i] += red[i + s];
        __syncthreads();
    }
    if (i == 0) alpha[o] = red[0] * (1.0 / 2304.0);
}

// ---------------------------------------------------------------- pack x signs
// grid (392, 4): blockIdx.y = word. xbits layout [pos][word] so the conv's
// per-lane 4-word gather is one contiguous 32B (2KB/wave, fully coalesced).
__global__ __launch_bounds__(256) void pack_x(const float* __restrict__ x,
                                              u64* __restrict__ xbits) {
    const int pos = blockIdx.x * 256 + threadIdx.x;    // 0 .. 100351
    const int word = blockIdx.y;                       // 0..3
    const int b = pos / N_SP;
    const int sp = pos - b * N_SP;
    const float* xp = x + ((size_t)b * C_IN + word * 64) * N_SP + sp;
    u64 m = 0;
#pragma unroll
    for (int j = 0; j < 64; ++j) {
        m |= (u64)(xp[(size_t)j * N_SP] > 0.0f) << j;
    }
    xbits[((size_t)pos << 2) + word] = m;
}

// ---------------------------------------------------------------- popcount conv
// grid (224, 64), block 256 = 4 waves. wave = one FULL output channel
// (c = blockIdx.y*4 + wave); lane = output column (56 active of 64).
// All 36 weight words live in SGPRs (readfirstlane). Each wave computes
// complete S values: no LDS, no __syncthreads, no cross-wave epilogue.
// R4's structure paid shuffles/LDS/epilogue per *quarter* output; this
// amortizes them over the full 4-word sum (wave count 229K -> 57K).
__global__ __launch_bounds__(256) void conv_popc(const u64* __restrict__ xbits,
                                                 const u64* __restrict__ wbits,
                                                 float* __restrict__ out,
                                                 u64* __restrict__ stats) {
    const int wave = threadIdx.x >> 6;
    const int lane = threadIdx.x & 63;
    const int tile = blockIdx.x;
    const int b = tile / 7;
    const int h0 = (tile % 7) * HT;
    const int c = (blockIdx.y << 2) + wave;
    const bool active = (lane < 56);
    const int wcl = active ? lane : 55;

    // 36 u64 weights -> 72 SGPRs (wave-uniform)
    unsigned wlo[9][4], whi[9][4];
    {
        const u64* wp = wbits + (size_t)c * 36;
#pragma unroll
        for (int t = 0; t < 9; ++t)
#pragma unroll
            for (int k = 0; k < 4; ++k) {
                u64 v = wp[t * 4 + k];
                wlo[t][k] = __builtin_amdgcn_readfirstlane((unsigned)v);
                whi[t][k] = __builtin_amdgcn_readfirstlane((unsigned)(v >> 32));
            }
    }

    // column base; row h lives at xb + h*56*4 (u64 elements)
    const u64* xb = xbits + (((size_t)b * N_SP + wcl) << 2);

    u64 r[3][4];   // rotating rows: at iter hh, top=r[hh%3], mid=r[(hh+1)%3], bot=r[(hh+2)%3]
#pragma unroll
    for (int k = 0; k < 4; ++k) {
        r[0][k] = xb[(size_t)((h0 > 0 ? h0 - 1 : 0) * 56) * 4 + k];   // garbage if h0==0 (unused)
        r[1][k] = xb[(size_t)(h0 * 56) * 4 + k];
        r[2][k] = xb[(size_t)((h0 + 1) * 56) * 4 + k];
    }

    int isum = 0;
    unsigned usq = 0;
    float* outc = out + ((size_t)b * C_OUT + c) * N_SP + h0 * 56 + lane;
    const int vc = 3 - (lane == 0) - (lane == 55);

#pragma unroll
    for (int hh = 0; hh < HT; ++hh) {
        const int h = h0 + hh;
        const u64* top = r[hh % 3];
        const u64* mid = r[(hh + 1) % 3];
        const u64* bot = r[(hh + 2) % 3];
        int Q0 = 0, Q1 = 0, Q2 = 0;
        if (h > 0) {
#pragma unroll
            for (int k = 0; k < 4; ++k) {
                unsigned lo = (unsigned)top[k], hi = (unsigned)(top[k] >> 32);
                Q0 += __popc(lo ^ wlo[0][k]) + __popc(hi ^ whi[0][k]);
                Q1 += __popc(lo ^ wlo[1][k]) + __popc(hi ^ whi[1][k]);
                Q2 += __popc(lo ^ wlo[2][k]) + __popc(hi ^ whi[2][k]);
            }
        }
#pragma unroll
        for (int k = 0; k < 4; ++k) {
            unsigned lo = (unsigned)mid[k], hi = (unsigned)(mid[k] >> 32);
            Q0 += __popc(lo ^ wlo[3][k]) + __popc(hi ^ whi[3][k]);
            Q1 += __popc(lo ^ wlo[4][k]) + __popc(hi ^ whi[4][k]);
            Q2 += __popc(lo ^ wlo[5][k]) + __popc(hi ^ whi[5][k]);
        }
        if (h < 55) {
#pragma unroll
            for (int k = 0; k < 4; ++k) {
                unsigned lo = (unsigned)bot[k], hi = (unsigned)(bot[k] >> 32);
                Q0 += __popc(lo ^ wlo[6][k]) + __popc(hi ^ whi[6][k]);
                Q1 += __popc(lo ^ wlo[7][k]) + __popc(hi ^ whi[7][k]);
                Q2 += __popc(lo ^ wlo[8][k]) + __popc(hi ^ whi[8][k]);
            }
        }
        if (!active) Q2 = 0;               // lane 55's R reads lane 56
        int L = __shfl_up(Q0, 1);
        if (lane == 0) L = 0;
        int R = __shfl_down(Q2, 1);
        const int nr = (h > 0) + 1 + (h < 55);
        int S = ((nr * vc) << 8) - ((L + Q1 + R) << 1);   // exact integer conv sum
        if (active) {
            outc[hh * 56] = (float)S;
            isum += S;
            usq += (unsigned)(S * S);
        }
        if (hh < HT - 1 && h + 2 < 56) {
            u64* dst = r[hh % 3];          // overwrite old top -> becomes new bottom
#pragma unroll
            for (int k = 0; k < 4; ++k) dst[k] = xb[(size_t)((h + 2) * 56) * 4 + k];
        }
    }

    // wave reduce (|isum| <= 1.04M, usq <= 2.38e9 — both fit 32-bit)
#pragma unroll
    for (int off = 32; off > 0; off >>= 1) {
        isum += __shfl_down(isum, off);
        usq += (unsigned)__shfl_down((int)usq, off);
    }
    if (lane == 0) {
        atomicAdd(&stats[c], (u64)(long long)isum);
        atomicAdd(&stats[C_OUT + c], (u64)usq);
    }
}

// ---------------------------------------------------------------- BN consts
__global__ void make_consts(const u64* __restrict__ stats,
                            const double* __restrict__ alpha,
                            const float* __restrict__ gamma,
                            const float* __restrict__ beta,
                            double* __restrict__ AB) {
    const int c = threadIdx.x;
    const double N = (double)(BATCH * N_SP);
    double s1 = (double)(long long)stats[c];
    double s2 = (double)(long long)stats[C_OUT + c];
    double mu = s1 / N;
    double var = s2 / N - mu * mu;
    double a = alpha[c];
    double vy = a * a * var;
    double scale = (double)gamma[c] / sqrt(vy + 1e-5);
    double A = a * scale;
    double B = (double)beta[c] - A * mu;
    AB[c] = A;
    AB[C_OUT + c] = B;
}

// ---------------------------------------------------------------- finalize
// In-place: d_out holds exact-integer S as float; out = (A*S+B > 0) ? 1 : 0.
__global__ __launch_bounds__(256) void finalize(float* __restrict__ out,
                                                const double* __restrict__ AB) {
    const unsigned i4 = blockIdx.x * 256 + threadIdx.x;   // 0 .. 6422527
    const unsigned e = i4 << 2;                            // element base
    const int c = (int)((e / N_SP) & (C_OUT - 1));         // 3136 | 4 -> c uniform in float4
    const double A = AB[c];
    const double B = AB[C_OUT + c];
    float4 v = ((float4*)out)[i4];
    v.x = (A * (double)v.x + B) > 0.0 ? 1.0f : 0.0f;
    v.y = (A * (double)v.y + B) > 0.0 ? 1.0f : 0.0f;
    v.z = (A * (double)v.z + B) > 0.0 ? 1.0f : 0.0f;
    v.w = (A * (double)v.w + B) > 0.0 ? 1.0f : 0.0f;
    ((float4*)out)[i4] = v;
}

// ---------------------------------------------------------------- launch
extern "C" void kernel_launch(void* const* d_in, const int* in_sizes, int n_in,
                              void* d_out, int out_size, void* d_ws, size_t ws_size,
                              hipStream_t stream) {
    const float* x      = (const float*)d_in[0];
    const float* weight = (const float*)d_in[1];
    const float* bias   = (const float*)d_in[2];   (void)bias;  // cancels in BN
    const float* gamma  = (const float*)d_in[3];
    const float* beta   = (const float*)d_in[4];
    float* out = (float*)d_out;

    char* ws = (char*)d_ws;
    u64*    stats = (u64*)(ws);                 // [512]
    double* alpha = (double*)(ws + 4096);       // [256]
    double* AB    = (double*)(ws + 8192);       // [512]
    u64*    wbits = (u64*)(ws + 16384);         // [256*9*4]
    u64*    xbits = (u64*)(ws + 98304);         // [32*3136][4]

    prep_weights<<<C_OUT, 256, 0, stream>>>(weight, wbits, alpha, stats);
    pack_x<<<dim3(BATCH * N_SP / 256, 4), 256, 0, stream>>>(x, xbits);
    conv_popc<<<dim3(BATCH * 7, C_OUT / 4), 256, 0, stream>>>(xbits, wbits, out, stats);
    make_consts<<<1, C_OUT, 0, stream>>>(stats, alpha, gamma, beta, AB);
    finalize<<<(out_size / 4) / 256, 256, 0, stream>>>(out, AB);
}